// Round 11
// baseline (289.553 us; speedup 1.0000x reference)
//
#include <hip/hip_runtime.h>
#include <hip/hip_bf16.h>
#include <stdint.h>

#define BATCH 8
#define CCH   512
#define NHD   8
#define HD    64
#define LLEN  4096
#define M1    1536

typedef __bf16 bf16x8 __attribute__((ext_vector_type(8)));
typedef __bf16 bf16x4 __attribute__((ext_vector_type(4)));
typedef float  f32x4  __attribute__((ext_vector_type(4)));

__device__ __forceinline__ f32x4 mfma16(bf16x8 a, bf16x8 b, f32x4 c) {
  return __builtin_amdgcn_mfma_f32_16x16x32_bf16(a, b, c, 0, 0, 0);
}

__device__ __forceinline__ void gload_lds16(const void* g, void* l) {
  __builtin_amdgcn_global_load_lds(
      (const __attribute__((address_space(1))) uint32_t*)(uintptr_t)g,
      (__attribute__((address_space(3))) uint32_t*)(uintptr_t)l,
      16, 0, 0);
}

// ---------------- pack weights/biases to bf16 ----------------
__global__ void pack_w(const float* __restrict__ wq, const float* __restrict__ wk,
                       const float* __restrict__ wv, const float* __restrict__ wo,
                       const float* __restrict__ bq, const float* __restrict__ bk,
                       const float* __restrict__ bv,
                       __bf16* __restrict__ wqkvb, __bf16* __restrict__ wob,
                       float* __restrict__ biasq) {
  const int n = M1 * CCH + CCH * CCH + M1;
  for (int i = blockIdx.x * blockDim.x + threadIdx.x; i < n; i += gridDim.x * blockDim.x) {
    if (i < M1 * CCH) {
      int r = i >> 9, c = i & 511;
      float v = (r < 512) ? wq[r * 512 + c]
              : (r < 1024) ? wk[(r - 512) * 512 + c]
                           : wv[(r - 1024) * 512 + c];
      wqkvb[i] = (__bf16)v;
    } else if (i < M1 * CCH + CCH * CCH) {
      int j = i - M1 * CCH;
      wob[j] = (__bf16)wo[j];
    } else {
      int j = i - M1 * CCH - CCH * CCH;
      biasq[j] = (j < 512) ? bq[j] : (j < 1024) ? bk[j - 512] : bv[j - 1024];
    }
  }
}

// ======== QKV GEMM with FUSED x-transpose ========
// 128x128, BK=32, dbuf 32KB LDS. A (weights) staged via gload_lds (r8 path).
// B (x) read fp32 coalesced from [b][c][l], cvt bf16 in regs, ds_write transposed
// into the r8 swizzled layout (row=l, 32 elems, chunk slot = ch ^ ((row>>1)&3)).
// B reg pipeline runs 2 tiles ahead of compute.
#define STG_A(tt, buf)                                                        \
  {                                                                           \
    const __bf16* As_ = Ag + (tt) * 32;                                       \
    __bf16* dA = lds + (buf) * 8192;                                          \
    gload_lds16(As_ + srcOff1, dA + tid * 8);                                 \
    gload_lds16(As_ + srcOff2, dA + tid * 8 + 2048);                          \
  }
#define LOADB(F, tt)                                                          \
  {                                                                           \
    const float* xr = xb + (size_t)((tt) * 32 + ch * 8) * LLEN + l0 + lp * 2; \
    _Pragma("unroll") for (int i = 0; i < 8; ++i)                             \
        F[i] = *(const float2*)(xr + (size_t)i * LLEN);                       \
  }
#define WRITEB(F, buf)                                                        \
  {                                                                           \
    bf16x8 v0, v1;                                                            \
    _Pragma("unroll") for (int i = 0; i < 8; ++i) {                           \
      v0[i] = (__bf16)F[i].x;                                                 \
      v1[i] = (__bf16)F[i].y;                                                 \
    }                                                                         \
    const int s8 = (ch ^ (lp & 3)) * 8;                                       \
    __bf16* dB = lds + (buf) * 8192 + 4096 + lp * 64 + s8;                    \
    *(bf16x8*)dB        = v0;                                                 \
    *(bf16x8*)(dB + 32) = v1;                                                 \
  }

__global__ __launch_bounds__(256, 3) void gemm_qkv(
    const __bf16* __restrict__ A, const float* __restrict__ x,
    const float* __restrict__ bias,
    __bf16* __restrict__ qt, __bf16* __restrict__ kcm, __bf16* __restrict__ vcm) {
  __shared__ __attribute__((aligned(16))) __bf16 lds[2 * 8192];  // 32KB
  const int b  = blockIdx.z;
  const int n0 = blockIdx.x * 128;
  const int m0 = blockIdx.y * 128;
  const int tid = threadIdx.x;
  const int ll = tid & 63, w = tid >> 6;
  const int wr = w >> 1, wc = w & 1;
  const int lhi = ll >> 4, llo = ll & 15;
  // B staging thread map: ch = chunk (8 c's), lp = l-pair
  const int ch = tid & 3, lp = tid >> 2;

  const int slotE = ((lhi ^ ((llo >> 1) & 3)) << 3);
  int aOff[4], bOff[4];
#pragma unroll
  for (int m = 0; m < 4; ++m) aOff[m] = (wr * 64 + m * 16 + llo) * 32 + slotE;
#pragma unroll
  for (int n = 0; n < 4; ++n) bOff[n] = 4096 + (wc * 64 + n * 16 + llo) * 32 + slotE;

  const int s1 = tid, s2 = tid + 256;
  const int r1 = s1 >> 2, r2s = s2 >> 2;
  const int srcOff1 = r1 * CCH + (((s1 & 3) ^ ((r1 >> 1) & 3)) << 3);
  const int srcOff2 = r2s * CCH + (((s2 & 3) ^ ((r2s >> 1) & 3)) << 3);

  const __bf16* Ag = A + (size_t)m0 * CCH;
  const float* xb = x + (size_t)b * CCH * LLEN;
  const int l0 = n0;

  f32x4 acc[4][4] = {};
  float2 F0[8], F1[8];

  // prologue: B tile0 -> buf0; B tile1 -> regs; A tile0 staged
  LOADB(F0, 0)
  WRITEB(F0, 0)
  LOADB(F1, 1)
  STG_A(0, 0)
  __syncthreads();

#pragma unroll
  for (int tt = 0; tt < 8; ++tt) {
    {  // t even: write F1 (tile t+1), load F0 (tile t+2)
      const int t = 2 * tt, buf = t & 1;
      if (t < 15) { STG_A(t + 1, buf ^ 1) WRITEB(F1, buf ^ 1) }
      if (t < 14) LOADB(F0, t + 2)
      bf16x8 af[4], bq[4];
      const __bf16* base = lds + buf * 8192;
#pragma unroll
      for (int m = 0; m < 4; ++m) af[m] = *(const bf16x8*)(base + aOff[m]);
#pragma unroll
      for (int n = 0; n < 4; ++n) bq[n] = *(const bf16x8*)(base + bOff[n]);
#pragma unroll
      for (int m = 0; m < 4; ++m)
#pragma unroll
        for (int n = 0; n < 4; ++n) acc[m][n] = mfma16(af[m], bq[n], acc[m][n]);
      __syncthreads();
    }
    {  // t odd: write F0 (tile t+1), load F1 (tile t+2)
      const int t = 2 * tt + 1, buf = t & 1;
      if (t < 15) { STG_A(t + 1, buf ^ 1) WRITEB(F0, buf ^ 1) }
      if (t < 14) LOADB(F1, t + 2)
      bf16x8 af[4], bq[4];
      const __bf16* base = lds + buf * 8192;
#pragma unroll
      for (int m = 0; m < 4; ++m) af[m] = *(const bf16x8*)(base + aOff[m]);
#pragma unroll
      for (int n = 0; n < 4; ++n) bq[n] = *(const bf16x8*)(base + bOff[n]);
#pragma unroll
      for (int m = 0; m < 4; ++m)
#pragma unroll
        for (int n = 0; n < 4; ++n) acc[m][n] = mfma16(af[m], bq[n], acc[m][n]);
      __syncthreads();
    }
  }

  // epilogue (r8 scalar form)
#pragma unroll
  for (int i = 0; i < 4; ++i) {
    const int o0 = m0 + wr * 64 + i * 16 + lhi * 4;
#pragma unroll
    for (int j = 0; j < 4; ++j) {
      const int col = n0 + wc * 64 + j * 16 + llo;
      if (m0 < 512) {
        bf16x4 pk;
#pragma unroll
        for (int r = 0; r < 4; ++r) {
          float tv = acc[i][j][r] + bias[o0 + r];
          tv = tv > 0.f ? tv + 1.f : __expf(tv);
          pk[r] = (__bf16)tv;
        }
        *(bf16x4*)(qt + ((size_t)b * LLEN + col) * CCH + o0) = pk;
      } else if (m0 < 1024) {
#pragma unroll
        for (int r = 0; r < 4; ++r) {
          float tv = acc[i][j][r] + bias[o0 + r];
          tv = tv > 0.f ? tv + 1.f : __expf(tv);
          kcm[((size_t)b * CCH + (o0 - 512 + r)) * LLEN + col] = (__bf16)tv;
        }
      } else {
#pragma unroll
        for (int r = 0; r < 4; ++r)
          vcm[((size_t)b * CCH + (o0 - 1024 + r)) * LLEN + col] =
              (__bf16)(acc[i][j][r] + bias[o0 + r]);
      }
    }
  }
}

// ======== out GEMM: r8 128x128 core, A = wob (batch-independent) ========
#define STG2(tt, buf)                                                        \
  {                                                                          \
    const __bf16* As_ = Ag + (tt) * 32;                                      \
    const __bf16* Bs_ = Bg + (tt) * 32;                                      \
    __bf16* dA = lds + (buf) * 8192;                                         \
    __bf16* dB = dA + 4096;                                                  \
    gload_lds16(As_ + srcOff1, dA + tid * 8);                                \
    gload_lds16(As_ + srcOff2, dA + tid * 8 + 2048);                         \
    gload_lds16(Bs_ + srcOff1, dB + tid * 8);                                \
    gload_lds16(Bs_ + srcOff2, dB + tid * 8 + 2048);                         \
  }

__global__ __launch_bounds__(256, 4) void gemm_out(
    const __bf16* __restrict__ A, const __bf16* __restrict__ Bm,
    const float* __restrict__ bias, float* __restrict__ out) {
  __shared__ __attribute__((aligned(16))) __bf16 lds[2 * 8192];
  const int b  = blockIdx.z;
  const int n0 = blockIdx.x * 128;
  const int m0 = blockIdx.y * 128;
  const int tid = threadIdx.x;
  const int ll = tid & 63, w = tid >> 6;
  const int wr = w >> 1, wc = w & 1;
  const int lhi = ll >> 4, llo = ll & 15;

  const int slotE = ((lhi ^ ((llo >> 1) & 3)) << 3);
  int aOff[4], bOff[4];
#pragma unroll
  for (int m = 0; m < 4; ++m) aOff[m] = (wr * 64 + m * 16 + llo) * 32 + slotE;
#pragma unroll
  for (int n = 0; n < 4; ++n) bOff[n] = 4096 + (wc * 64 + n * 16 + llo) * 32 + slotE;

  const int s1 = tid, s2 = tid + 256;
  const int r1 = s1 >> 2, r2s = s2 >> 2;
  const int srcOff1 = r1 * CCH + (((s1 & 3) ^ ((r1 >> 1) & 3)) << 3);
  const int srcOff2 = r2s * CCH + (((s2 & 3) ^ ((r2s >> 1) & 3)) << 3);

  const __bf16* Ag = A + (size_t)m0 * CCH;
  const __bf16* Bg = Bm + ((size_t)b * LLEN + n0) * CCH;

  f32x4 acc[4][4] = {};

  STG2(0, 0)
  __syncthreads();

  for (int t = 0; t < 16; ++t) {
    const int buf = t & 1;
    if (t < 15) STG2(t + 1, buf ^ 1)
    bf16x8 af[4], bfr[4];
    const __bf16* base = lds + buf * 8192;
#pragma unroll
    for (int m = 0; m < 4; ++m) af[m] = *(const bf16x8*)(base + aOff[m]);
#pragma unroll
    for (int n = 0; n < 4; ++n) bfr[n] = *(const bf16x8*)(base + bOff[n]);
#pragma unroll
    for (int m = 0; m < 4; ++m)
#pragma unroll
      for (int n = 0; n < 4; ++n) acc[m][n] = mfma16(af[m], bfr[n], acc[m][n]);
    __syncthreads();
  }

#pragma unroll
  for (int i = 0; i < 4; ++i) {
    const int o0 = m0 + wr * 64 + i * 16 + lhi * 4;
#pragma unroll
    for (int j = 0; j < 4; ++j) {
      const int col = n0 + wc * 64 + j * 16 + llo;
#pragma unroll
      for (int r = 0; r < 4; ++r)
        out[((size_t)b * CCH + o0 + r) * LLEN + col] = acc[i][j][r] + bias[o0 + r];
    }
  }
}

// ---------------- KV partials + fused Ksum partials (4 waves, LDS reduce) ----------------
__global__ __launch_bounds__(256) void kv_part_k(const __bf16* __restrict__ kcm,
                                                 const __bf16* __restrict__ vcm,
                                                 float* __restrict__ part,
                                                 float* __restrict__ part_ks) {
  __shared__ float red[8192];
  __shared__ float ksred[4][64];
  const int lc = blockIdx.x, bh = blockIdx.y;
  const int b = bh >> 3, h = bh & 7;
  const int tid = threadIdx.x;
  const int w = tid >> 6, ll = tid & 63, lhi = ll >> 4, llo = ll & 15;
  const __bf16* Kp = kcm + ((size_t)b * CCH + h * 64) * LLEN;
  const __bf16* Vp = vcm + ((size_t)b * CCH + h * 64) * LLEN;
  f32x4 acc[4][4];
#pragma unroll
  for (int i = 0; i < 4; ++i)
#pragma unroll
    for (int j = 0; j < 4; ++j) acc[i][j] = (f32x4){0.f, 0.f, 0.f, 0.f};
  float ks[4] = {0.f, 0.f, 0.f, 0.f};
  const int base = lc * 512 + w * 128 + lhi * 8;
#pragma unroll
  for (int kt = 0; kt < 4; ++kt) {
    const int k0 = base + kt * 32;
    bf16x8 af[4], bfr[4];
#pragma unroll
    for (int i = 0; i < 4; ++i) af[i]  = *(const bf16x8*)(Kp + (size_t)(i * 16 + llo) * LLEN + k0);
#pragma unroll
    for (int i = 0; i < 4; ++i) bfr[i] = *(const bf16x8*)(Vp + (size_t)(i * 16 + llo) * LLEN + k0);
#pragma unroll
    for (int i = 0; i < 4; ++i)
#pragma unroll
      for (int r = 0; r < 8; ++r) ks[i] += (float)af[i][r];
#pragma unroll
    for (int i = 0; i < 4; ++i)
#pragma unroll
      for (int j = 0; j < 4; ++j) acc[i][j] = mfma16(af[i], bfr[j], acc[i][j]);
  }
#pragma unroll
  for (int i = 0; i < 4; ++i) {
    float s = ks[i];
    s += __shfl_xor(s, 16);
    s += __shfl_xor(s, 32);
    if (lhi == 0) ksred[w][i * 16 + llo] = s;
  }
  if (w >= 2) {
#pragma unroll
    for (int i = 0; i < 4; ++i)
#pragma unroll
      for (int j = 0; j < 4; ++j)
        *(f32x4*)(red + (((w - 2) * 16 + i * 4 + j) << 8) + ll * 4) = acc[i][j];
  }
  __syncthreads();
  if (w < 2) {
#pragma unroll
    for (int i = 0; i < 4; ++i)
#pragma unroll
      for (int j = 0; j < 4; ++j)
        acc[i][j] += *(const f32x4*)(red + ((w * 16 + i * 4 + j) << 8) + ll * 4);
  }
  float ksv = 0.f;
  if (w == 1) ksv = ksred[0][ll] + ksred[1][ll] + ksred[2][ll] + ksred[3][ll];
  __syncthreads();
  if (w == 1) {
#pragma unroll
    for (int i = 0; i < 4; ++i)
#pragma unroll
      for (int j = 0; j < 4; ++j)
        *(f32x4*)(red + ((i * 4 + j) << 8) + ll * 4) = acc[i][j];
    part_ks[((size_t)lc * 64 + bh) * 64 + ll] = ksv;
  }
  __syncthreads();
  if (w == 0) {
    float* op = part + ((size_t)lc * 64 + bh) * 4096;
#pragma unroll
    for (int i = 0; i < 4; ++i)
#pragma unroll
      for (int j = 0; j < 4; ++j) {
        acc[i][j] += *(const f32x4*)(red + ((i * 4 + j) << 8) + ll * 4);
#pragma unroll
        for (int r = 0; r < 4; ++r) {
          int d = i * 16 + lhi * 4 + r, v = j * 16 + llo;
          op[d * 64 + v] = acc[i][j][r];
        }
      }
  }
}

__global__ void kv_red_k(const float* __restrict__ part, float* __restrict__ kv) {
  const int i = blockIdx.x * blockDim.x + threadIdx.x;
  float s = 0.f;
#pragma unroll
  for (int lc = 0; lc < 8; ++lc) s += part[(size_t)lc * 262144 + i];
  kv[i] = s;
}

__global__ void ksum_red_k(const float* __restrict__ part_ks, float* __restrict__ ksum) {
  const int i = blockIdx.x * blockDim.x + threadIdx.x;
  float s = 0.f;
#pragma unroll
  for (int lc = 0; lc < 8; ++lc) s += part_ks[(size_t)lc * 4096 + i];
  ksum[i] = s;
}

// ---------------- apply: attn[b][l][h*64+v] = (sum_d Q[l,d]KV[d,v]) * Z[l] ----------------
__global__ __launch_bounds__(256) void apply_k(const __bf16* __restrict__ qt,
                                               const float* __restrict__ kv,
                                               const float* __restrict__ ksum,
                                               __bf16* __restrict__ attn) {
  __shared__ __attribute__((aligned(16))) __bf16 kvT[64 * 68];
  __shared__ float zb[256];
  const int lc = blockIdx.x, bh = blockIdx.y;
  const int b = bh >> 3, h = bh & 7;
  const int tid = threadIdx.x;
  const float* kvp = kv + (size_t)bh * 4096;
  for (int i = tid; i < 4096; i += 256) {
    int d = i >> 6, v = i & 63;
    kvT[v * 68 + d] = (__bf16)kvp[i];
  }
  const int l = lc * 256 + tid;
  const __bf16* qp = qt + ((size_t)b * LLEN + l) * CCH + h * 64;
  const float* ksp = ksum + bh * 64;
  float s = 0.f;
#pragma unroll
  for (int d8 = 0; d8 < 64; d8 += 8) {
    bf16x8 qv = *(const bf16x8*)(qp + d8);
#pragma unroll
    for (int i = 0; i < 8; ++i) s += (float)qv[i] * ksp[d8 + i];
  }
  zb[tid] = 1.0f / (s + 1e-6f);
  __syncthreads();

  const int ll = tid & 63, w = tid >> 6, lhi = ll >> 4, llo = ll & 15;
  f32x4 acc[4][4];
#pragma unroll
  for (int i = 0; i < 4; ++i)
#pragma unroll
    for (int j = 0; j < 4; ++j) acc[i][j] = (f32x4){0.f, 0.f, 0.f, 0.f};
  const __bf16* qbase = qt + ((size_t)b * LLEN + lc * 256 + w * 64) * CCH + h * 64;
#pragma unroll
  for (int kt = 0; kt < 2; ++kt) {
    const int k8 = kt * 32 + lhi * 8;
    bf16x8 af[4], bfr[4];
#pragma unroll
    for (int i = 0; i < 4; ++i)
      af[i] = *(const bf16x8*)(qbase + (size_t)(i * 16 + llo) * CCH + k8);
#pragma unroll
    for (int j = 0; j < 4; ++j) {
      const __bf16* pb = kvT + (j * 16 + llo) * 68 + k8;
      ((bf16x4*)&bfr[j])[0] = *(const bf16x4*)pb;
      ((bf16x4*)&bfr[j])[1] = *(const bf16x4*)(pb + 4);
    }
#pragma unroll
    for (int i = 0; i < 4; ++i)
#pragma unroll
      for (int j = 0; j < 4; ++j) acc[i][j] = mfma16(af[i], bfr[j], acc[i][j]);
  }
  __bf16* ap = attn + ((size_t)b * LLEN + lc * 256) * CCH + h * 64;
#pragma unroll
  for (int i = 0; i < 4; ++i)
#pragma unroll
    for (int j = 0; j < 4; ++j)
#pragma unroll
      for (int r = 0; r < 4; ++r) {
        int ml = w * 64 + i * 16 + lhi * 4 + r;
        int v = j * 16 + llo;
        ap[(size_t)ml * CCH + v] = (__bf16)(acc[i][j][r] * zb[ml]);
      }
}

extern "C" void kernel_launch(void* const* d_in, const int* in_sizes, int n_in,
                              void* d_out, int out_size, void* d_ws, size_t ws_size,
                              hipStream_t stream) {
  const float* x  = (const float*)d_in[0];
  const float* wq = (const float*)d_in[1];
  const float* bq = (const float*)d_in[2];
  const float* wk = (const float*)d_in[3];
  const float* bk = (const float*)d_in[4];
  const float* wv = (const float*)d_in[5];
  const float* bv = (const float*)d_in[6];
  const float* wo = (const float*)d_in[7];
  const float* bo = (const float*)d_in[8];
  float* out = (float*)d_out;

  char* p = (char*)d_ws;
  __bf16* attn  = (__bf16*)p; p += (size_t)BATCH * LLEN * CCH * 2;  // 32MB
  __bf16* qt    = (__bf16*)p; p += (size_t)BATCH * LLEN * CCH * 2;  // 32MB
  __bf16* kcm   = (__bf16*)p; p += (size_t)BATCH * CCH * LLEN * 2;  // 32MB
  __bf16* vcm   = (__bf16*)p; p += (size_t)BATCH * CCH * LLEN * 2;  // 32MB
  __bf16* wqkvb = (__bf16*)p; p += (size_t)M1 * CCH * 2;
  __bf16* wob   = (__bf16*)p; p += (size_t)CCH * CCH * 2;
  float*  biasq = (float*)p;  p += (size_t)M1 * 4;
  float*  ksum  = (float*)p;  p += (size_t)BATCH * CCH * 4;
  float*  part  = (float*)p;  p += (size_t)8 * 64 * HD * HD * 4;    // 8MB
  float*  kvb   = (float*)p;  p += (size_t)64 * HD * HD * 4;        // 1MB
  float*  pks   = (float*)p;  p += (size_t)8 * 64 * 64 * 4;         // 128KB

  pack_w<<<1024, 256, 0, stream>>>(wq, wk, wv, wo, bq, bk, bv, wqkvb, wob, biasq);
  gemm_qkv<<<dim3(32, 12, BATCH), 256, 0, stream>>>(wqkvb, x, biasq, qt, kcm, vcm);
  kv_part_k<<<dim3(8, 64), 256, 0, stream>>>(kcm, vcm, part, pks);
  kv_red_k<<<1024, 256, 0, stream>>>(part, kvb);
  ksum_red_k<<<16, 256, 0, stream>>>(pks, ksum);
  apply_k<<<dim3(16, 64), 256, 0, stream>>>(qt, kvb, ksum, attn);
  gemm_out<<<dim3(32, 4, BATCH), 256, 0, stream>>>(wob, attn, bo, out);
}

// Round 12
// 168.613 us; speedup vs baseline: 1.7173x; 1.7173x over previous
//
#include <hip/hip_runtime.h>
#include <hip/hip_bf16.h>
#include <stdint.h>

#define BATCH 8
#define CCH   512
#define NHD   8
#define HD    64
#define LLEN  4096
#define M1    1536

typedef __bf16 bf16x8 __attribute__((ext_vector_type(8)));
typedef __bf16 bf16x4 __attribute__((ext_vector_type(4)));
typedef float  f32x4  __attribute__((ext_vector_type(4)));

__device__ __forceinline__ f32x4 mfma16(bf16x8 a, bf16x8 b, f32x4 c) {
  return __builtin_amdgcn_mfma_f32_16x16x32_bf16(a, b, c, 0, 0, 0);
}

__device__ __forceinline__ void gload_lds16(const void* g, void* l) {
  __builtin_amdgcn_global_load_lds(
      (const __attribute__((address_space(1))) uint32_t*)(uintptr_t)g,
      (__attribute__((address_space(3))) uint32_t*)(uintptr_t)l,
      16, 0, 0);
}

// ---------------- pack weights/biases to bf16 ----------------
__global__ void pack_w(const float* __restrict__ wq, const float* __restrict__ wk,
                       const float* __restrict__ wv, const float* __restrict__ wo,
                       const float* __restrict__ bq, const float* __restrict__ bk,
                       const float* __restrict__ bv,
                       __bf16* __restrict__ wqkvb, __bf16* __restrict__ wob,
                       float* __restrict__ biasq) {
  const int n = M1 * CCH + CCH * CCH + M1;
  for (int i = blockIdx.x * blockDim.x + threadIdx.x; i < n; i += gridDim.x * blockDim.x) {
    if (i < M1 * CCH) {
      int r = i >> 9, c = i & 511;
      float v = (r < 512) ? wq[r * 512 + c]
              : (r < 1024) ? wk[(r - 512) * 512 + c]
                           : wv[(r - 1024) * 512 + c];
      wqkvb[i] = (__bf16)v;
    } else if (i < M1 * CCH + CCH * CCH) {
      int j = i - M1 * CCH;
      wob[j] = (__bf16)wo[j];
    } else {
      int j = i - M1 * CCH - CCH * CCH;
      biasq[j] = (j < 512) ? bq[j] : (j < 1024) ? bk[j - 512] : bv[j - 1024];
    }
  }
}

// ---------------- x [b][C][L] fp32 -> xt [b][L][C] bf16 (64x64 tiles) ----------------
__global__ __launch_bounds__(256) void transpose_x(const float* __restrict__ x,
                                                   __bf16* __restrict__ xt) {
  __shared__ float tile[64][65];
  const int b = blockIdx.z, c0 = blockIdx.y * 64, l0 = blockIdx.x * 64;
  const int t = threadIdx.x;
  const int lq = (t & 15) * 4, cr = t >> 4;
  const float* xp = x + ((size_t)b * CCH + c0) * LLEN + l0;
#pragma unroll
  for (int q = 0; q < 4; ++q) {
    const int c = cr + q * 16;
    float4 v = *(const float4*)(xp + (size_t)c * LLEN + lq);
    tile[c][lq + 0] = v.x;
    tile[c][lq + 1] = v.y;
    tile[c][lq + 2] = v.z;
    tile[c][lq + 3] = v.w;
  }
  __syncthreads();
  __bf16* xo = xt + ((size_t)b * LLEN + l0) * CCH + c0;
  const int c8 = (t & 7) * 8, lr = t >> 3;
#pragma unroll
  for (int p = 0; p < 2; ++p) {
    const int l = lr + p * 32;
    bf16x8 o;
#pragma unroll
    for (int i = 0; i < 8; ++i) o[i] = (__bf16)tile[c8 + i][l];
    *(bf16x8*)(xo + (size_t)l * CCH + c8) = o;
  }
}

// ======== 128x128 GEMM, BK=32, dbuf 32KB LDS, 4 waves, 4 blocks/CU (r8 core) ========
// Swizzle (0-conflict, verified): row's 16B chunk c stored at slot c ^ ((row>>1)&3).
// Loop: stage(t+1) -> frag reads(t) -> MFMA -> __syncthreads(). Scalar epilogues
// (measured faster than LDS-transposed epilogues in r9).
#define STG128(tt, buf)                                                      \
  {                                                                          \
    const __bf16* As_ = Ag + (tt) * 32;                                      \
    const __bf16* Bs_ = Bg + (tt) * 32;                                      \
    __bf16* dA = lds + (buf) * 8192;                                         \
    __bf16* dB = dA + 4096;                                                  \
    gload_lds16(As_ + srcOff1, dA + tid * 8);                                \
    gload_lds16(As_ + srcOff2, dA + tid * 8 + 2048);                         \
    gload_lds16(Bs_ + srcOff1, dB + tid * 8);                                \
    gload_lds16(Bs_ + srcOff2, dB + tid * 8 + 2048);                         \
  }

template <int EPI>
__global__ __launch_bounds__(256, 4) void gemm128(
    const __bf16* __restrict__ A, const __bf16* __restrict__ Bm,
    const float* __restrict__ bias,
    __bf16* __restrict__ qt, __bf16* __restrict__ kcm, __bf16* __restrict__ vcm,
    float* __restrict__ out) {
  __shared__ __attribute__((aligned(16))) __bf16 lds[2 * 8192];  // 32KB
  const int b  = blockIdx.z;
  const int n0 = blockIdx.x * 128;
  const int m0 = blockIdx.y * 128;
  const int tid = threadIdx.x;
  const int ll = tid & 63, w = tid >> 6;
  const int wr = w >> 1, wc = w & 1;
  const int lhi = ll >> 4, llo = ll & 15;

  const int slotE = ((lhi ^ ((llo >> 1) & 3)) << 3);
  int aOff[4], bOff[4];
#pragma unroll
  for (int m = 0; m < 4; ++m) aOff[m] = (wr * 64 + m * 16 + llo) * 32 + slotE;
#pragma unroll
  for (int n = 0; n < 4; ++n) bOff[n] = 4096 + (wc * 64 + n * 16 + llo) * 32 + slotE;

  const int s1 = tid, s2 = tid + 256;
  const int r1 = s1 >> 2, r2s = s2 >> 2;
  const int srcOff1 = r1 * CCH + (((s1 & 3) ^ ((r1 >> 1) & 3)) << 3);
  const int srcOff2 = r2s * CCH + (((s2 & 3) ^ ((r2s >> 1) & 3)) << 3);

  const __bf16* Ag = A + (size_t)m0 * CCH;
  const __bf16* Bg = Bm + ((size_t)b * LLEN + n0) * CCH;

  f32x4 acc[4][4] = {};

  STG128(0, 0)
  __syncthreads();  // tile0 resident (barrier drains vmcnt)

  for (int t = 0; t < 16; ++t) {
    const int buf = t & 1;
    if (t < 15) STG128(t + 1, buf ^ 1)
    bf16x8 af[4], bfr[4];
    const __bf16* base = lds + buf * 8192;
#pragma unroll
    for (int m = 0; m < 4; ++m) af[m] = *(const bf16x8*)(base + aOff[m]);
#pragma unroll
    for (int n = 0; n < 4; ++n) bfr[n] = *(const bf16x8*)(base + bOff[n]);
#pragma unroll
    for (int m = 0; m < 4; ++m)
#pragma unroll
      for (int n = 0; n < 4; ++n) acc[m][n] = mfma16(af[m], bfr[n], acc[m][n]);
    __syncthreads();  // drains vmcnt -> next buffer resident
  }

  // epilogue (scalar, r8 form — measured best)
#pragma unroll
  for (int i = 0; i < 4; ++i) {
    const int o0 = m0 + wr * 64 + i * 16 + lhi * 4;
#pragma unroll
    for (int j = 0; j < 4; ++j) {
      const int col = n0 + wc * 64 + j * 16 + llo;
      if (EPI == 0) {
        if (m0 < 512) {
          bf16x4 pk;
#pragma unroll
          for (int r = 0; r < 4; ++r) {
            float tv = acc[i][j][r] + bias[o0 + r];
            tv = tv > 0.f ? tv + 1.f : __expf(tv);
            pk[r] = (__bf16)tv;
          }
          *(bf16x4*)(qt + ((size_t)b * LLEN + col) * CCH + o0) = pk;
        } else if (m0 < 1024) {
#pragma unroll
          for (int r = 0; r < 4; ++r) {
            float tv = acc[i][j][r] + bias[o0 + r];
            tv = tv > 0.f ? tv + 1.f : __expf(tv);
            kcm[((size_t)b * CCH + (o0 - 512 + r)) * LLEN + col] = (__bf16)tv;
          }
        } else {
#pragma unroll
          for (int r = 0; r < 4; ++r)
            vcm[((size_t)b * CCH + (o0 - 1024 + r)) * LLEN + col] =
                (__bf16)(acc[i][j][r] + bias[o0 + r]);
        }
      } else {
#pragma unroll
        for (int r = 0; r < 4; ++r)
          out[((size_t)b * CCH + o0 + r) * LLEN + col] = acc[i][j][r] + bias[o0 + r];
      }
    }
  }
}

// ---------------- KV partials + fused Ksum partials (4 waves, LDS reduce) ----------------
__global__ __launch_bounds__(256) void kv_part_k(const __bf16* __restrict__ kcm,
                                                 const __bf16* __restrict__ vcm,
                                                 float* __restrict__ part,
                                                 float* __restrict__ part_ks) {
  __shared__ float red[8192];
  __shared__ float ksred[4][64];
  const int lc = blockIdx.x, bh = blockIdx.y;
  const int b = bh >> 3, h = bh & 7;
  const int tid = threadIdx.x;
  const int w = tid >> 6, ll = tid & 63, lhi = ll >> 4, llo = ll & 15;
  const __bf16* Kp = kcm + ((size_t)b * CCH + h * 64) * LLEN;
  const __bf16* Vp = vcm + ((size_t)b * CCH + h * 64) * LLEN;
  f32x4 acc[4][4];
#pragma unroll
  for (int i = 0; i < 4; ++i)
#pragma unroll
    for (int j = 0; j < 4; ++j) acc[i][j] = (f32x4){0.f, 0.f, 0.f, 0.f};
  float ks[4] = {0.f, 0.f, 0.f, 0.f};
  const int base = lc * 512 + w * 128 + lhi * 8;
#pragma unroll
  for (int kt = 0; kt < 4; ++kt) {
    const int k0 = base + kt * 32;
    bf16x8 af[4], bfr[4];
#pragma unroll
    for (int i = 0; i < 4; ++i) af[i]  = *(const bf16x8*)(Kp + (size_t)(i * 16 + llo) * LLEN + k0);
#pragma unroll
    for (int i = 0; i < 4; ++i) bfr[i] = *(const bf16x8*)(Vp + (size_t)(i * 16 + llo) * LLEN + k0);
#pragma unroll
    for (int i = 0; i < 4; ++i)
#pragma unroll
      for (int r = 0; r < 8; ++r) ks[i] += (float)af[i][r];
#pragma unroll
    for (int i = 0; i < 4; ++i)
#pragma unroll
      for (int j = 0; j < 4; ++j) acc[i][j] = mfma16(af[i], bfr[j], acc[i][j]);
  }
#pragma unroll
  for (int i = 0; i < 4; ++i) {
    float s = ks[i];
    s += __shfl_xor(s, 16);
    s += __shfl_xor(s, 32);
    if (lhi == 0) ksred[w][i * 16 + llo] = s;
  }
  if (w >= 2) {
#pragma unroll
    for (int i = 0; i < 4; ++i)
#pragma unroll
      for (int j = 0; j < 4; ++j)
        *(f32x4*)(red + (((w - 2) * 16 + i * 4 + j) << 8) + ll * 4) = acc[i][j];
  }
  __syncthreads();
  if (w < 2) {
#pragma unroll
    for (int i = 0; i < 4; ++i)
#pragma unroll
      for (int j = 0; j < 4; ++j)
        acc[i][j] += *(const f32x4*)(red + ((w * 16 + i * 4 + j) << 8) + ll * 4);
  }
  float ksv = 0.f;
  if (w == 1) ksv = ksred[0][ll] + ksred[1][ll] + ksred[2][ll] + ksred[3][ll];
  __syncthreads();
  if (w == 1) {
#pragma unroll
    for (int i = 0; i < 4; ++i)
#pragma unroll
      for (int j = 0; j < 4; ++j)
        *(f32x4*)(red + ((i * 4 + j) << 8) + ll * 4) = acc[i][j];
    part_ks[((size_t)lc * 64 + bh) * 64 + ll] = ksv;
  }
  __syncthreads();
  if (w == 0) {
    float* op = part + ((size_t)lc * 64 + bh) * 4096;
#pragma unroll
    for (int i = 0; i < 4; ++i)
#pragma unroll
      for (int j = 0; j < 4; ++j) {
        acc[i][j] += *(const f32x4*)(red + ((i * 4 + j) << 8) + ll * 4);
#pragma unroll
        for (int r = 0; r < 4; ++r) {
          int d = i * 16 + lhi * 4 + r, v = j * 16 + llo;
          op[d * 64 + v] = acc[i][j][r];
        }
      }
  }
}

// ---- merged reduction: kv (262144 elems) + ksum (4096 elems) in one launch ----
__global__ void red_k(const float* __restrict__ part, const float* __restrict__ pks,
                      float* __restrict__ kv, float* __restrict__ ksum) {
  const int bid = blockIdx.x;
  const int t = threadIdx.x;
  if (bid < 1024) {
    const int i = bid * 256 + t;
    float s = 0.f;
#pragma unroll
    for (int lc = 0; lc < 8; ++lc) s += part[(size_t)lc * 262144 + i];
    kv[i] = s;
  } else {
    const int i = (bid - 1024) * 256 + t;
    float s = 0.f;
#pragma unroll
    for (int lc = 0; lc < 8; ++lc) s += pks[(size_t)lc * 4096 + i];
    ksum[i] = s;
  }
}

// ---------------- apply: attn[b][l][h*64+v] = (sum_d Q[l,d]KV[d,v]) * Z[l] ----------------
__global__ __launch_bounds__(256) void apply_k(const __bf16* __restrict__ qt,
                                               const float* __restrict__ kv,
                                               const float* __restrict__ ksum,
                                               __bf16* __restrict__ attn) {
  __shared__ __attribute__((aligned(16))) __bf16 kvT[64 * 68];
  __shared__ float zb[256];
  const int lc = blockIdx.x, bh = blockIdx.y;
  const int b = bh >> 3, h = bh & 7;
  const int tid = threadIdx.x;
  const float* kvp = kv + (size_t)bh * 4096;
  for (int i = tid; i < 4096; i += 256) {
    int d = i >> 6, v = i & 63;
    kvT[v * 68 + d] = (__bf16)kvp[i];
  }
  const int l = lc * 256 + tid;
  const __bf16* qp = qt + ((size_t)b * LLEN + l) * CCH + h * 64;
  const float* ksp = ksum + bh * 64;
  float s = 0.f;
#pragma unroll
  for (int d8 = 0; d8 < 64; d8 += 8) {
    bf16x8 qv = *(const bf16x8*)(qp + d8);
#pragma unroll
    for (int i = 0; i < 8; ++i) s += (float)qv[i] * ksp[d8 + i];
  }
  zb[tid] = 1.0f / (s + 1e-6f);
  __syncthreads();

  const int ll = tid & 63, w = tid >> 6, lhi = ll >> 4, llo = ll & 15;
  f32x4 acc[4][4];
#pragma unroll
  for (int i = 0; i < 4; ++i)
#pragma unroll
    for (int j = 0; j < 4; ++j) acc[i][j] = (f32x4){0.f, 0.f, 0.f, 0.f};
  const __bf16* qbase = qt + ((size_t)b * LLEN + lc * 256 + w * 64) * CCH + h * 64;
#pragma unroll
  for (int kt = 0; kt < 2; ++kt) {
    const int k8 = kt * 32 + lhi * 8;
    bf16x8 af[4], bfr[4];
#pragma unroll
    for (int i = 0; i < 4; ++i)
      af[i] = *(const bf16x8*)(qbase + (size_t)(i * 16 + llo) * CCH + k8);
#pragma unroll
    for (int j = 0; j < 4; ++j) {
      const __bf16* pb = kvT + (j * 16 + llo) * 68 + k8;
      ((bf16x4*)&bfr[j])[0] = *(const bf16x4*)pb;
      ((bf16x4*)&bfr[j])[1] = *(const bf16x4*)(pb + 4);
    }
#pragma unroll
    for (int i = 0; i < 4; ++i)
#pragma unroll
      for (int j = 0; j < 4; ++j) acc[i][j] = mfma16(af[i], bfr[j], acc[i][j]);
  }
  __bf16* ap = attn + ((size_t)b * LLEN + lc * 256) * CCH + h * 64;
#pragma unroll
  for (int i = 0; i < 4; ++i)
#pragma unroll
    for (int j = 0; j < 4; ++j)
#pragma unroll
      for (int r = 0; r < 4; ++r) {
        int ml = w * 64 + i * 16 + lhi * 4 + r;
        int v = j * 16 + llo;
        ap[(size_t)ml * CCH + v] = (__bf16)(acc[i][j][r] * zb[ml]);
      }
}

extern "C" void kernel_launch(void* const* d_in, const int* in_sizes, int n_in,
                              void* d_out, int out_size, void* d_ws, size_t ws_size,
                              hipStream_t stream) {
  const float* x  = (const float*)d_in[0];
  const float* wq = (const float*)d_in[1];
  const float* bq = (const float*)d_in[2];
  const float* wk = (const float*)d_in[3];
  const float* bk = (const float*)d_in[4];
  const float* wv = (const float*)d_in[5];
  const float* bv = (const float*)d_in[6];
  const float* wo = (const float*)d_in[7];
  const float* bo = (const float*)d_in[8];
  float* out = (float*)d_out;

  char* p = (char*)d_ws;
  __bf16* xt    = (__bf16*)p; p += (size_t)BATCH * LLEN * CCH * 2;  // 32MB (reused as attn)
  __bf16* qt    = (__bf16*)p; p += (size_t)BATCH * LLEN * CCH * 2;  // 32MB
  __bf16* kcm   = (__bf16*)p; p += (size_t)BATCH * CCH * LLEN * 2;  // 32MB
  __bf16* vcm   = (__bf16*)p; p += (size_t)BATCH * CCH * LLEN * 2;  // 32MB
  __bf16* wqkvb = (__bf16*)p; p += (size_t)M1 * CCH * 2;
  __bf16* wob   = (__bf16*)p; p += (size_t)CCH * CCH * 2;
  float*  biasq = (float*)p;  p += (size_t)M1 * 4;
  float*  ksum  = (float*)p;  p += (size_t)BATCH * CCH * 4;
  float*  part  = (float*)p;  p += (size_t)8 * 64 * HD * HD * 4;    // 8MB
  float*  kvb   = (float*)p;  p += (size_t)64 * HD * HD * 4;        // 1MB
  float*  pks   = (float*)p;  p += (size_t)8 * 64 * 64 * 4;         // 128KB
  __bf16* attn  = xt;

  pack_w<<<1024, 256, 0, stream>>>(wq, wk, wv, wo, bq, bk, bv, wqkvb, wob, biasq);
  transpose_x<<<dim3(64, 8, BATCH), 256, 0, stream>>>(x, xt);
  gemm128<0><<<dim3(32, 12, BATCH), 256, 0, stream>>>(wqkvb, xt, biasq, qt, kcm, vcm, nullptr);
  kv_part_k<<<dim3(8, 64), 256, 0, stream>>>(kcm, vcm, part, pks);
  red_k<<<1040, 256, 0, stream>>>(part, pks, kvb, ksum);
  apply_k<<<dim3(16, 64), 256, 0, stream>>>(qt, kvb, ksum, attn);
  gemm128<1><<<dim3(32, 4, BATCH), 256, 0, stream>>>(wob, attn, bo, nullptr, nullptr,
                                                     nullptr, out);
}

// Round 14
// 166.359 us; speedup vs baseline: 1.7405x; 1.0135x over previous
//
#include <hip/hip_runtime.h>
#include <hip/hip_bf16.h>
#include <stdint.h>

#define BATCH 8
#define CCH   512
#define NHD   8
#define HD    64
#define LLEN  4096
#define M1    1536

typedef __bf16 bf16x8 __attribute__((ext_vector_type(8)));
typedef __bf16 bf16x4 __attribute__((ext_vector_type(4)));
typedef float  f32x4  __attribute__((ext_vector_type(4)));

__device__ __forceinline__ f32x4 mfma16(bf16x8 a, bf16x8 b, f32x4 c) {
  return __builtin_amdgcn_mfma_f32_16x16x32_bf16(a, b, c, 0, 0, 0);
}

__device__ __forceinline__ void gload_lds16(const void* g, void* l) {
  __builtin_amdgcn_global_load_lds(
      (const __attribute__((address_space(1))) uint32_t*)(uintptr_t)g,
      (__attribute__((address_space(3))) uint32_t*)(uintptr_t)l,
      16, 0, 0);
}

// ---------------- pack weights/biases to bf16 ----------------
__global__ void pack_w(const float* __restrict__ wq, const float* __restrict__ wk,
                       const float* __restrict__ wv, const float* __restrict__ wo,
                       const float* __restrict__ bq, const float* __restrict__ bk,
                       const float* __restrict__ bv,
                       __bf16* __restrict__ wqkvb, __bf16* __restrict__ wob,
                       float* __restrict__ biasq) {
  const int n = M1 * CCH + CCH * CCH + M1;
  for (int i = blockIdx.x * blockDim.x + threadIdx.x; i < n; i += gridDim.x * blockDim.x) {
    if (i < M1 * CCH) {
      int r = i >> 9, c = i & 511;
      float v = (r < 512) ? wq[r * 512 + c]
              : (r < 1024) ? wk[(r - 512) * 512 + c]
                           : wv[(r - 1024) * 512 + c];
      wqkvb[i] = (__bf16)v;
    } else if (i < M1 * CCH + CCH * CCH) {
      int j = i - M1 * CCH;
      wob[j] = (__bf16)wo[j];
    } else {
      int j = i - M1 * CCH - CCH * CCH;
      biasq[j] = (j < 512) ? bq[j] : (j < 1024) ? bk[j - 512] : bv[j - 1024];
    }
  }
}

// ---------------- x [b][C][L] fp32 -> xt [b][L][C] bf16 (64x64 tiles) ----------------
__global__ __launch_bounds__(256) void transpose_x(const float* __restrict__ x,
                                                   __bf16* __restrict__ xt) {
  __shared__ float tile[64][65];
  const int b = blockIdx.z, c0 = blockIdx.y * 64, l0 = blockIdx.x * 64;
  const int t = threadIdx.x;
  const int lq = (t & 15) * 4, cr = t >> 4;
  const float* xp = x + ((size_t)b * CCH + c0) * LLEN + l0;
#pragma unroll
  for (int q = 0; q < 4; ++q) {
    const int c = cr + q * 16;
    float4 v = *(const float4*)(xp + (size_t)c * LLEN + lq);
    tile[c][lq + 0] = v.x;
    tile[c][lq + 1] = v.y;
    tile[c][lq + 2] = v.z;
    tile[c][lq + 3] = v.w;
  }
  __syncthreads();
  __bf16* xo = xt + ((size_t)b * LLEN + l0) * CCH + c0;
  const int c8 = (t & 7) * 8, lr = t >> 3;
#pragma unroll
  for (int p = 0; p < 2; ++p) {
    const int l = lr + p * 32;
    bf16x8 o;
#pragma unroll
    for (int i = 0; i < 8; ++i) o[i] = (__bf16)tile[c8 + i][l];
    *(bf16x8*)(xo + (size_t)l * CCH + c8) = o;
  }
}

// ======== 256x256 8-phase GEMM: BK=64, 8 waves, 2x64KB dbuf, race-free schedule ======
// Reads per dbuf: P1{a0,b0} P2{b1} P3{a1}. Stages (region last-read proof in comments):
// P1:A0(u)->d1  P2:A1(u)->d1  P3:B0(t+2)->d0  P4:B1(t+2)->d0 +vmcnt(4)
// P5:A0(t+2)->d0 P6:A1(t+2)->d0 P7:B0(t+3)->d1 P8:B1(t+3)->d1 +vmcnt(4)
// vmcnt(4) at P4 drains {prevP7,prevP8,P1,P2} = tile u's 4 halves (needed P5-P8).
// vmcnt(4) at P8 drains {P3..P6} = tile t+2's 4 halves (needed next P1-P4).
#define STAGEH(Gp, ktile, rowbase, region, dbase)                              \
  {                                                                            \
    const __bf16* sp_ = (Gp) + (size_t)(rowbase)*CCH + (ktile) * 64 + srcOff;  \
    __bf16* dp_ = lds + (dbase) + (region) + tid * 8;                          \
    gload_lds16(sp_, dp_);                                                     \
    gload_lds16(sp_ + 64 * CCH, dp_ + 4096);                                   \
  }
#define RD_A(areg, dbase, mbase)                                               \
  _Pragma("unroll") for (int mf = 0; mf < 4; ++mf) {                           \
    const int o_ = (dbase) + aBase + ((mbase) + mf) * 1024;                    \
    areg[mf][0] = *(const bf16x8*)(lds + o_);                                  \
    areg[mf][1] = *(const bf16x8*)(lds + (o_ ^ 32));                           \
  }
#define RD_B(breg, dbase, nbase)                                               \
  _Pragma("unroll") for (int nf = 0; nf < 2; ++nf) {                           \
    const int o_ = (dbase) + bBase + ((nbase) + nf) * 1024;                    \
    breg[nf][0] = *(const bf16x8*)(lds + o_);                                  \
    breg[nf][1] = *(const bf16x8*)(lds + (o_ ^ 32));                           \
  }
#define MMQ(areg, breg, mb, nb)                                                \
  __builtin_amdgcn_s_setprio(1);                                               \
  _Pragma("unroll") for (int mf = 0; mf < 4; ++mf)                             \
    _Pragma("unroll") for (int nf = 0; nf < 2; ++nf) {                         \
      acc[(mb) + mf][(nb) + nf] =                                              \
          mfma16(areg[mf][0], breg[nf][0], acc[(mb) + mf][(nb) + nf]);         \
      acc[(mb) + mf][(nb) + nf] =                                              \
          mfma16(areg[mf][1], breg[nf][1], acc[(mb) + mf][(nb) + nf]);         \
    }                                                                          \
  __builtin_amdgcn_s_setprio(0);
#define BARW                                                                   \
  __builtin_amdgcn_s_barrier();                                                \
  asm volatile("s_waitcnt lgkmcnt(0)" ::: "memory");                           \
  __builtin_amdgcn_sched_barrier(0);
#define BAR __builtin_amdgcn_s_barrier();
#define VM4 asm volatile("s_waitcnt vmcnt(4)" ::: "memory");
#define VM0 asm volatile("s_waitcnt vmcnt(0)" ::: "memory");

template <int EPI>
__global__ __launch_bounds__(512, 1) void gemm256p(
    const __bf16* __restrict__ A, const __bf16* __restrict__ Bm,
    const float* __restrict__ bias,
    __bf16* __restrict__ qt, __bf16* __restrict__ kcm, __bf16* __restrict__ vcm,
    float* __restrict__ out) {
  __shared__ __attribute__((aligned(16))) __bf16 lds[65536];  // 128KB
  const int b  = blockIdx.z;
  const int n0 = blockIdx.x * 256;
  const int m0 = blockIdx.y * 256;
  const int tid = threadIdx.x;
  const int ll = tid & 63, w = tid >> 6;  // 8 waves
  const int wr = w >> 2, wc = w & 3;      // 2M x 4N, wave tile 128x64
  const int lhi = ll >> 4, llo = ll & 15;

  // frag bases (elems); ks=1 chunk = lhi+4 -> slot^4 -> elem offset ^32
  const int slot0 = lhi ^ (llo & 7);
  const int aBase = wr * 8192 + llo * 64 + slot0 * 8;
  const int bBase = 16384 + (wc >> 1) * 8192 + ((wc & 1) * 64 + llo) * 64 + slot0 * 8;

  // staging decode (inverse swizzle): 16B slot s=tid -> row s>>3, chunk (s&7)^(row&7)
  const int r1 = tid >> 3;
  const int srcOff = r1 * CCH + (((tid & 7) ^ (r1 & 7)) << 3);

  const __bf16* Ag = A + (size_t)m0 * CCH;
  const __bf16* Bg = Bm + ((size_t)b * LLEN + n0) * CCH;

  f32x4 acc[8][4] = {};
  bf16x8 a0[4][2], a1[4][2], b0[2][2], b1[2][2];

  // prologue: d0 = tile0 (4 halves), d1.B = tile1 B halves; drain tile0
  STAGEH(Ag, 0, 0,   0,     0)
  STAGEH(Ag, 0, 128, 8192,  0)
  STAGEH(Bg, 0, 0,   16384, 0)
  STAGEH(Bg, 0, 128, 24576, 0)
  STAGEH(Bg, 1, 0,   16384, 32768)
  STAGEH(Bg, 1, 128, 24576, 32768)
  VM4   // drain tile0's 8 loads; tile1 B (4) stay in flight
  BAR

#pragma unroll
  for (int i = 0; i < 4; ++i) {
    const int t = 2 * i, u = t + 1;
    const bool sp = (i < 3);
    // ---- P1: reads d0{a0,b0}; stage A0(u)->d1 (d1.A0 last read prev P5/P7) ----
    RD_A(a0, 0, 0)
    RD_B(b0, 0, 0)
    STAGEH(Ag, u, 0, 0, 32768)
    asm volatile("s_waitcnt lgkmcnt(8)" ::: "memory");
    BARW
    MMQ(a0, b0, 0, 0)
    BAR
    // ---- P2: read d0{b1}; stage A1(u)->d1 ----
    RD_B(b1, 0, 2)
    STAGEH(Ag, u, 128, 8192, 32768)
    BARW
    MMQ(a0, b1, 0, 2)
    BAR
    // ---- P3: read d0{a1}; stage B0(t+2)->d0 (d0.B0 last read P2) ----
    RD_A(a1, 0, 4)
    if (sp) STAGEH(Bg, t + 2, 0, 16384, 0)
    BARW
    MMQ(a1, b0, 4, 0)
    BAR
    // ---- P4: stage B1(t+2)->d0; vmcnt checkpoint (tile u resident) ----
    if (sp) { STAGEH(Bg, t + 2, 128, 24576, 0) VM4 }
    else    { VM0 }
    BARW
    MMQ(a1, b1, 4, 2)
    BAR
    // ---- P5: reads d1{a0,b0}; stage A0(t+2)->d0 (d0.A0 last read P3) ----
    RD_A(a0, 32768, 0)
    RD_B(b0, 32768, 0)
    if (sp) STAGEH(Ag, t + 2, 0, 0, 0)
    asm volatile("s_waitcnt lgkmcnt(8)" ::: "memory");
    BARW
    MMQ(a0, b0, 0, 0)
    BAR
    // ---- P6: read d1{b1}; stage A1(t+2)->d0 ----
    RD_B(b1, 32768, 2)
    if (sp) STAGEH(Ag, t + 2, 128, 8192, 0)
    BARW
    MMQ(a0, b1, 0, 2)
    BAR
    // ---- P7: read d1{a1}; stage B0(t+3)->d1 (d1.B0 last read P6) ----
    RD_A(a1, 32768, 4)
    if (sp) STAGEH(Bg, t + 3, 0, 16384, 32768)
    BARW
    MMQ(a1, b0, 4, 0)
    BAR
    // ---- P8: stage B1(t+3)->d1; vmcnt checkpoint (tile t+2 resident) ----
    if (sp) { STAGEH(Bg, t + 3, 128, 24576, 32768) VM4 }
    BARW
    MMQ(a1, b1, 4, 2)
    BAR
  }

  // epilogue (scalar, r8 form — measured best)
#pragma unroll
  for (int i = 0; i < 8; ++i) {
    const int o0 = m0 + wr * 128 + i * 16 + lhi * 4;
#pragma unroll
    for (int j = 0; j < 4; ++j) {
      const int col = n0 + wc * 64 + j * 16 + llo;
      if (EPI == 0) {
        if (m0 < 512) {
          bf16x4 pk;
#pragma unroll
          for (int r = 0; r < 4; ++r) {
            float tv = acc[i][j][r] + bias[o0 + r];
            tv = tv > 0.f ? tv + 1.f : __expf(tv);
            pk[r] = (__bf16)tv;
          }
          *(bf16x4*)(qt + ((size_t)b * LLEN + col) * CCH + o0) = pk;
        } else if (m0 < 1024) {
#pragma unroll
          for (int r = 0; r < 4; ++r) {
            float tv = acc[i][j][r] + bias[o0 + r];
            tv = tv > 0.f ? tv + 1.f : __expf(tv);
            kcm[((size_t)b * CCH + (o0 - 512 + r)) * LLEN + col] = (__bf16)tv;
          }
        } else {
#pragma unroll
          for (int r = 0; r < 4; ++r)
            vcm[((size_t)b * CCH + (o0 - 1024 + r)) * LLEN + col] =
                (__bf16)(acc[i][j][r] + bias[o0 + r]);
        }
      } else {
#pragma unroll
        for (int r = 0; r < 4; ++r)
          out[((size_t)b * CCH + o0 + r) * LLEN + col] = acc[i][j][r] + bias[o0 + r];
      }
    }
  }
}

// ---------------- KV partials + fused Ksum partials (4 waves, LDS reduce) ----------------
__global__ __launch_bounds__(256) void kv_part_k(const __bf16* __restrict__ kcm,
                                                 const __bf16* __restrict__ vcm,
                                                 float* __restrict__ part,
                                                 float* __restrict__ part_ks) {
  __shared__ float red[8192];
  __shared__ float ksred[4][64];
  const int lc = blockIdx.x, bh = blockIdx.y;
  const int b = bh >> 3, h = bh & 7;
  const int tid = threadIdx.x;
  const int w = tid >> 6, ll = tid & 63, lhi = ll >> 4, llo = ll & 15;
  const __bf16* Kp = kcm + ((size_t)b * CCH + h * 64) * LLEN;
  const __bf16* Vp = vcm + ((size_t)b * CCH + h * 64) * LLEN;
  f32x4 acc[4][4];
#pragma unroll
  for (int i = 0; i < 4; ++i)
#pragma unroll
    for (int j = 0; j < 4; ++j) acc[i][j] = (f32x4){0.f, 0.f, 0.f, 0.f};
  float ks[4] = {0.f, 0.f, 0.f, 0.f};
  const int base = lc * 512 + w * 128 + lhi * 8;
#pragma unroll
  for (int kt = 0; kt < 4; ++kt) {
    const int k0 = base + kt * 32;
    bf16x8 af[4], bfr[4];
#pragma unroll
    for (int i = 0; i < 4; ++i) af[i]  = *(const bf16x8*)(Kp + (size_t)(i * 16 + llo) * LLEN + k0);
#pragma unroll
    for (int i = 0; i < 4; ++i) bfr[i] = *(const bf16x8*)(Vp + (size_t)(i * 16 + llo) * LLEN + k0);
#pragma unroll
    for (int i = 0; i < 4; ++i)
#pragma unroll
      for (int r = 0; r < 8; ++r) ks[i] += (float)af[i][r];
#pragma unroll
    for (int i = 0; i < 4; ++i)
#pragma unroll
      for (int j = 0; j < 4; ++j) acc[i][j] = mfma16(af[i], bfr[j], acc[i][j]);
  }
#pragma unroll
  for (int i = 0; i < 4; ++i) {
    float s = ks[i];
    s += __shfl_xor(s, 16);
    s += __shfl_xor(s, 32);
    if (lhi == 0) ksred[w][i * 16 + llo] = s;
  }
  if (w >= 2) {
#pragma unroll
    for (int i = 0; i < 4; ++i)
#pragma unroll
      for (int j = 0; j < 4; ++j)
        *(f32x4*)(red + (((w - 2) * 16 + i * 4 + j) << 8) + ll * 4) = acc[i][j];
  }
  __syncthreads();
  if (w < 2) {
#pragma unroll
    for (int i = 0; i < 4; ++i)
#pragma unroll
      for (int j = 0; j < 4; ++j)
        acc[i][j] += *(const f32x4*)(red + ((w * 16 + i * 4 + j) << 8) + ll * 4);
  }
  float ksv = 0.f;
  if (w == 1) ksv = ksred[0][ll] + ksred[1][ll] + ksred[2][ll] + ksred[3][ll];
  __syncthreads();
  if (w == 1) {
#pragma unroll
    for (int i = 0; i < 4; ++i)
#pragma unroll
      for (int j = 0; j < 4; ++j)
        *(f32x4*)(red + ((i * 4 + j) << 8) + ll * 4) = acc[i][j];
    part_ks[((size_t)lc * 64 + bh) * 64 + ll] = ksv;
  }
  __syncthreads();
  if (w == 0) {
    float* op = part + ((size_t)lc * 64 + bh) * 4096;
#pragma unroll
    for (int i = 0; i < 4; ++i)
#pragma unroll
      for (int j = 0; j < 4; ++j) {
        acc[i][j] += *(const f32x4*)(red + ((i * 4 + j) << 8) + ll * 4);
#pragma unroll
        for (int r = 0; r < 4; ++r) {
          int d = i * 16 + lhi * 4 + r, v = j * 16 + llo;
          op[d * 64 + v] = acc[i][j][r];
        }
      }
  }
}

// ---- merged reduction: kv (262144 elems) + ksum (4096 elems) in one launch ----
__global__ void red_k(const float* __restrict__ part, const float* __restrict__ pks,
                      float* __restrict__ kv, float* __restrict__ ksum) {
  const int bid = blockIdx.x;
  const int t = threadIdx.x;
  if (bid < 1024) {
    const int i = bid * 256 + t;
    float s = 0.f;
#pragma unroll
    for (int lc = 0; lc < 8; ++lc) s += part[(size_t)lc * 262144 + i];
    kv[i] = s;
  } else {
    const int i = (bid - 1024) * 256 + t;
    float s = 0.f;
#pragma unroll
    for (int lc = 0; lc < 8; ++lc) s += pks[(size_t)lc * 4096 + i];
    ksum[i] = s;
  }
}

// ---------------- apply: attn[b][l][h*64+v] = (sum_d Q[l,d]KV[d,v]) * Z[l] ----------------
__global__ __launch_bounds__(256) void apply_k(const __bf16* __restrict__ qt,
                                               const float* __restrict__ kv,
                                               const float* __restrict__ ksum,
                                               __bf16* __restrict__ attn) {
  __shared__ __attribute__((aligned(16))) __bf16 kvT[64 * 68];
  __shared__ float zb[256];
  const int lc = blockIdx.x, bh = blockIdx.y;
  const int b = bh >> 3, h = bh & 7;
  const int tid = threadIdx.x;
  const float* kvp = kv + (size_t)bh * 4096;
  for (int i = tid; i < 4096; i += 256) {
    int d = i >> 6, v = i & 63;
    kvT[v * 68 + d] = (__bf16)kvp[i];
  }
  const int l = lc * 256 + tid;
  const __bf16* qp = qt + ((size_t)b * LLEN + l) * CCH + h * 64;
  const float* ksp = ksum + bh * 64;
  float s = 0.f;
#pragma unroll
  for (int d8 = 0; d8 < 64; d8 += 8) {
    bf16x8 qv = *(const bf16x8*)(qp + d8);
#pragma unroll
    for (int i = 0; i < 8; ++i) s += (float)qv[i] * ksp[d8 + i];
  }
  zb[tid] = 1.0f / (s + 1e-6f);
  __syncthreads();

  const int ll = tid & 63, w = tid >> 6, lhi = ll >> 4, llo = ll & 15;
  f32x4 acc[4][4];
#pragma unroll
  for (int i = 0; i < 4; ++i)
#pragma unroll
    for (int j = 0; j < 4; ++j) acc[i][j] = (f32x4){0.f, 0.f, 0.f, 0.f};
  const __bf16* qbase = qt + ((size_t)b * LLEN + lc * 256 + w * 64) * CCH + h * 64;
#pragma unroll
  for (int kt = 0; kt < 2; ++kt) {
    const int k8 = kt * 32 + lhi * 8;
    bf16x8 af[4], bfr[4];
#pragma unroll
    for (int i = 0; i < 4; ++i)
      af[i] = *(const bf16x8*)(qbase + (size_t)(i * 16 + llo) * CCH + k8);
#pragma unroll
    for (int j = 0; j < 4; ++j) {
      const __bf16* pb = kvT + (j * 16 + llo) * 68 + k8;
      ((bf16x4*)&bfr[j])[0] = *(const bf16x4*)pb;
      ((bf16x4*)&bfr[j])[1] = *(const bf16x4*)(pb + 4);
    }
#pragma unroll
    for (int i = 0; i < 4; ++i)
#pragma unroll
      for (int j = 0; j < 4; ++j) acc[i][j] = mfma16(af[i], bfr[j], acc[i][j]);
  }
  __bf16* ap = attn + ((size_t)b * LLEN + lc * 256) * CCH + h * 64;
#pragma unroll
  for (int i = 0; i < 4; ++i)
#pragma unroll
    for (int j = 0; j < 4; ++j)
#pragma unroll
      for (int r = 0; r < 4; ++r) {
        int ml = w * 64 + i * 16 + lhi * 4 + r;
        int v = j * 16 + llo;
        ap[(size_t)ml * CCH + v] = (__bf16)(acc[i][j][r] * zb[ml]);
      }
}

extern "C" void kernel_launch(void* const* d_in, const int* in_sizes, int n_in,
                              void* d_out, int out_size, void* d_ws, size_t ws_size,
                              hipStream_t stream) {
  const float* x  = (const float*)d_in[0];
  const float* wq = (const float*)d_in[1];
  const float* bq = (const float*)d_in[2];
  const float* wk = (const float*)d_in[3];
  const float* bk = (const float*)d_in[4];
  const float* wv = (const float*)d_in[5];
  const float* bv = (const float*)d_in[6];
  const float* wo = (const float*)d_in[7];
  const float* bo = (const float*)d_in[8];
  float* out = (float*)d_out;

  char* p = (char*)d_ws;
  __bf16* xt    = (__bf16*)p; p += (size_t)BATCH * LLEN * CCH * 2;  // 32MB (reused as attn)
  __bf16* qt    = (__bf16*)p; p += (size_t)BATCH * LLEN * CCH * 2;  // 32MB
  __bf16* kcm   = (__bf16*)p; p += (size_t)BATCH * CCH * LLEN * 2;  // 32MB
  __bf16* vcm   = (__bf16*)p; p += (size_t)BATCH * CCH * LLEN * 2;  // 32MB
  __bf16* wqkvb = (__bf16*)p; p += (size_t)M1 * CCH * 2;
  __bf16* wob   = (__bf16*)p; p += (size_t)CCH * CCH * 2;
  float*  biasq = (float*)p;  p += (size_t)M1 * 4;
  float*  ksum  = (float*)p;  p += (size_t)BATCH * CCH * 4;
  float*  part  = (float*)p;  p += (size_t)8 * 64 * HD * HD * 4;    // 8MB
  float*  kvb   = (float*)p;  p += (size_t)64 * HD * HD * 4;        // 1MB
  float*  pks   = (float*)p;  p += (size_t)8 * 64 * 64 * 4;         // 128KB
  __bf16* attn  = xt;

  pack_w<<<1024, 256, 0, stream>>>(wq, wk, wv, wo, bq, bk, bv, wqkvb, wob, biasq);
  transpose_x<<<dim3(64, 8, BATCH), 256, 0, stream>>>(x, xt);
  gemm256p<0><<<dim3(16, 6, BATCH), 512, 0, stream>>>(wqkvb, xt, biasq, qt, kcm, vcm, nullptr);
  kv_part_k<<<dim3(8, 64), 256, 0, stream>>>(kcm, vcm, part, pks);
  red_k<<<1040, 256, 0, stream>>>(part, pks, kvb, ksum);
  apply_k<<<dim3(16, 64), 256, 0, stream>>>(qt, kvb, ksum, attn);
  gemm256p<1><<<dim3(16, 2, BATCH), 512, 0, stream>>>(wob, attn, bo, nullptr, nullptr,
                                                      nullptr, out);
}

// Round 15
// 165.957 us; speedup vs baseline: 1.7447x; 1.0024x over previous
//
#include <hip/hip_runtime.h>
#include <hip/hip_bf16.h>
#include <stdint.h>

#define BATCH 8
#define CCH   512
#define NHD   8
#define HD    64
#define LLEN  4096
#define M1    1536

typedef __bf16 bf16x8 __attribute__((ext_vector_type(8)));
typedef __bf16 bf16x4 __attribute__((ext_vector_type(4)));
typedef float  f32x4  __attribute__((ext_vector_type(4)));

__device__ __forceinline__ f32x4 mfma16(bf16x8 a, bf16x8 b, f32x4 c) {
  return __builtin_amdgcn_mfma_f32_16x16x32_bf16(a, b, c, 0, 0, 0);
}

__device__ __forceinline__ void gload_lds16(const void* g, void* l) {
  __builtin_amdgcn_global_load_lds(
      (const __attribute__((address_space(1))) uint32_t*)(uintptr_t)g,
      (__attribute__((address_space(3))) uint32_t*)(uintptr_t)l,
      16, 0, 0);
}

// ---------------- pack weights/biases to bf16 ----------------
__global__ void pack_w(const float* __restrict__ wq, const float* __restrict__ wk,
                       const float* __restrict__ wv, const float* __restrict__ wo,
                       const float* __restrict__ bq, const float* __restrict__ bk,
                       const float* __restrict__ bv,
                       __bf16* __restrict__ wqkvb, __bf16* __restrict__ wob,
                       float* __restrict__ biasq) {
  const int n = M1 * CCH + CCH * CCH + M1;
  for (int i = blockIdx.x * blockDim.x + threadIdx.x; i < n; i += gridDim.x * blockDim.x) {
    if (i < M1 * CCH) {
      int r = i >> 9, c = i & 511;
      float v = (r < 512) ? wq[r * 512 + c]
              : (r < 1024) ? wk[(r - 512) * 512 + c]
                           : wv[(r - 1024) * 512 + c];
      wqkvb[i] = (__bf16)v;
    } else if (i < M1 * CCH + CCH * CCH) {
      int j = i - M1 * CCH;
      wob[j] = (__bf16)wo[j];
    } else {
      int j = i - M1 * CCH - CCH * CCH;
      biasq[j] = (j < 512) ? bq[j] : (j < 1024) ? bk[j - 512] : bv[j - 1024];
    }
  }
}

// ---------------- x [b][C][L] fp32 -> xt [b][L][C] bf16 (64x64 tiles) ----------------
__global__ __launch_bounds__(256) void transpose_x(const float* __restrict__ x,
                                                   __bf16* __restrict__ xt) {
  __shared__ float tile[64][65];
  const int b = blockIdx.z, c0 = blockIdx.y * 64, l0 = blockIdx.x * 64;
  const int t = threadIdx.x;
  const int lq = (t & 15) * 4, cr = t >> 4;
  const float* xp = x + ((size_t)b * CCH + c0) * LLEN + l0;
#pragma unroll
  for (int q = 0; q < 4; ++q) {
    const int c = cr + q * 16;
    float4 v = *(const float4*)(xp + (size_t)c * LLEN + lq);
    tile[c][lq + 0] = v.x;
    tile[c][lq + 1] = v.y;
    tile[c][lq + 2] = v.z;
    tile[c][lq + 3] = v.w;
  }
  __syncthreads();
  __bf16* xo = xt + ((size_t)b * LLEN + l0) * CCH + c0;
  const int c8 = (t & 7) * 8, lr = t >> 3;
#pragma unroll
  for (int p = 0; p < 2; ++p) {
    const int l = lr + p * 32;
    bf16x8 o;
#pragma unroll
    for (int i = 0; i < 8; ++i) o[i] = (__bf16)tile[c8 + i][l];
    *(bf16x8*)(xo + (size_t)l * CCH + c8) = o;
  }
}

// ======== 128x128 GEMM, BK=32, TRIPLE-buffered 48KB LDS, prefetch dist 2, ========
// counted vmcnt(4) (tile t+1 loads stay in flight across barrier), 3 blocks/CU.
// Swizzle (0-conflict, verified): row's 16B chunk c stored at slot c ^ ((row>>1)&3).
// Race proof: stage buf(t+2)%3 == buf(t-1)%3, last read before iter t-1's barrier.
// vmcnt(4) at iter t: outstanding = {tile t+1 (4), tile t+2 (4)} -> drains t+1 exactly.
#define STG128(tt, bufidx)                                                   \
  {                                                                          \
    const __bf16* As_ = Ag + (tt) * 32;                                      \
    const __bf16* Bs_ = Bg + (tt) * 32;                                      \
    __bf16* dA = lds + (bufidx) * 8192;                                      \
    __bf16* dB = dA + 4096;                                                  \
    gload_lds16(As_ + srcOff1, dA + tid * 8);                                \
    gload_lds16(As_ + srcOff2, dA + tid * 8 + 2048);                         \
    gload_lds16(Bs_ + srcOff1, dB + tid * 8);                                \
    gload_lds16(Bs_ + srcOff2, dB + tid * 8 + 2048);                         \
  }

template <int EPI>
__global__ __launch_bounds__(256, 3) void gemm128t(
    const __bf16* __restrict__ A, const __bf16* __restrict__ Bm,
    const float* __restrict__ bias,
    __bf16* __restrict__ qt, __bf16* __restrict__ kcm, __bf16* __restrict__ vcm,
    float* __restrict__ out) {
  __shared__ __attribute__((aligned(16))) __bf16 lds[3 * 8192];  // 48KB
  const int b  = blockIdx.z;
  const int n0 = blockIdx.x * 128;
  const int m0 = blockIdx.y * 128;
  const int tid = threadIdx.x;
  const int ll = tid & 63, w = tid >> 6;
  const int wr = w >> 1, wc = w & 1;
  const int lhi = ll >> 4, llo = ll & 15;

  const int slotE = ((lhi ^ ((llo >> 1) & 3)) << 3);
  int aOff[4], bOff[4];
#pragma unroll
  for (int m = 0; m < 4; ++m) aOff[m] = (wr * 64 + m * 16 + llo) * 32 + slotE;
#pragma unroll
  for (int n = 0; n < 4; ++n) bOff[n] = 4096 + (wc * 64 + n * 16 + llo) * 32 + slotE;

  const int s1 = tid, s2 = tid + 256;
  const int r1 = s1 >> 2, r2s = s2 >> 2;
  const int srcOff1 = r1 * CCH + (((s1 & 3) ^ ((r1 >> 1) & 3)) << 3);
  const int srcOff2 = r2s * CCH + (((s2 & 3) ^ ((r2s >> 1) & 3)) << 3);

  const __bf16* Ag = A + (size_t)m0 * CCH;
  const __bf16* Bg = Bm + ((size_t)b * LLEN + n0) * CCH;

  f32x4 acc[4][4] = {};

  // prologue: tiles 0,1 staged; drain tile0 only (tile1 stays in flight)
  STG128(0, 0)
  STG128(1, 1)
  asm volatile("s_waitcnt vmcnt(4)" ::: "memory");
  __builtin_amdgcn_s_barrier();
  __builtin_amdgcn_sched_barrier(0);

  int bufc = 0, bufs = 2;
  for (int t = 0; t < 16; ++t) {
    if (t < 14) STG128(t + 2, bufs)
    bf16x8 af[4], bfr[4];
    const __bf16* base = lds + bufc * 8192;
#pragma unroll
    for (int m = 0; m < 4; ++m) af[m] = *(const bf16x8*)(base + aOff[m]);
#pragma unroll
    for (int n = 0; n < 4; ++n) bfr[n] = *(const bf16x8*)(base + bOff[n]);
#pragma unroll
    for (int m = 0; m < 4; ++m)
#pragma unroll
      for (int n = 0; n < 4; ++n) acc[m][n] = mfma16(af[m], bfr[n], acc[m][n]);
    if (t < 14)       asm volatile("s_waitcnt vmcnt(4)" ::: "memory");
    else if (t == 14) asm volatile("s_waitcnt vmcnt(0)" ::: "memory");
    __builtin_amdgcn_s_barrier();
    __builtin_amdgcn_sched_barrier(0);
    bufc = (bufc == 2) ? 0 : bufc + 1;
    bufs = (bufs == 2) ? 0 : bufs + 1;
  }

  // epilogue (scalar, r8 form — measured best)
#pragma unroll
  for (int i = 0; i < 4; ++i) {
    const int o0 = m0 + wr * 64 + i * 16 + lhi * 4;
#pragma unroll
    for (int j = 0; j < 4; ++j) {
      const int col = n0 + wc * 64 + j * 16 + llo;
      if (EPI == 0) {
        if (m0 < 512) {
          bf16x4 pk;
#pragma unroll
          for (int r = 0; r < 4; ++r) {
            float tv = acc[i][j][r] + bias[o0 + r];
            tv = tv > 0.f ? tv + 1.f : __expf(tv);
            pk[r] = (__bf16)tv;
          }
          *(bf16x4*)(qt + ((size_t)b * LLEN + col) * CCH + o0) = pk;
        } else if (m0 < 1024) {
#pragma unroll
          for (int r = 0; r < 4; ++r) {
            float tv = acc[i][j][r] + bias[o0 + r];
            tv = tv > 0.f ? tv + 1.f : __expf(tv);
            kcm[((size_t)b * CCH + (o0 - 512 + r)) * LLEN + col] = (__bf16)tv;
          }
        } else {
#pragma unroll
          for (int r = 0; r < 4; ++r)
            vcm[((size_t)b * CCH + (o0 - 1024 + r)) * LLEN + col] =
                (__bf16)(acc[i][j][r] + bias[o0 + r]);
        }
      } else {
#pragma unroll
        for (int r = 0; r < 4; ++r)
          out[((size_t)b * CCH + o0 + r) * LLEN + col] = acc[i][j][r] + bias[o0 + r];
      }
    }
  }
}

// ---------------- KV partials + fused Ksum partials (4 waves, LDS reduce) ----------------
__global__ __launch_bounds__(256) void kv_part_k(const __bf16* __restrict__ kcm,
                                                 const __bf16* __restrict__ vcm,
                                                 float* __restrict__ part,
                                                 float* __restrict__ part_ks) {
  __shared__ float red[8192];
  __shared__ float ksred[4][64];
  const int lc = blockIdx.x, bh = blockIdx.y;
  const int b = bh >> 3, h = bh & 7;
  const int tid = threadIdx.x;
  const int w = tid >> 6, ll = tid & 63, lhi = ll >> 4, llo = ll & 15;
  const __bf16* Kp = kcm + ((size_t)b * CCH + h * 64) * LLEN;
  const __bf16* Vp = vcm + ((size_t)b * CCH + h * 64) * LLEN;
  f32x4 acc[4][4];
#pragma unroll
  for (int i = 0; i < 4; ++i)
#pragma unroll
    for (int j = 0; j < 4; ++j) acc[i][j] = (f32x4){0.f, 0.f, 0.f, 0.f};
  float ks[4] = {0.f, 0.f, 0.f, 0.f};
  const int base = lc * 512 + w * 128 + lhi * 8;
#pragma unroll
  for (int kt = 0; kt < 4; ++kt) {
    const int k0 = base + kt * 32;
    bf16x8 af[4], bfr[4];
#pragma unroll
    for (int i = 0; i < 4; ++i) af[i]  = *(const bf16x8*)(Kp + (size_t)(i * 16 + llo) * LLEN + k0);
#pragma unroll
    for (int i = 0; i < 4; ++i) bfr[i] = *(const bf16x8*)(Vp + (size_t)(i * 16 + llo) * LLEN + k0);
#pragma unroll
    for (int i = 0; i < 4; ++i)
#pragma unroll
      for (int r = 0; r < 8; ++r) ks[i] += (float)af[i][r];
#pragma unroll
    for (int i = 0; i < 4; ++i)
#pragma unroll
      for (int j = 0; j < 4; ++j) acc[i][j] = mfma16(af[i], bfr[j], acc[i][j]);
  }
#pragma unroll
  for (int i = 0; i < 4; ++i) {
    float s = ks[i];
    s += __shfl_xor(s, 16);
    s += __shfl_xor(s, 32);
    if (lhi == 0) ksred[w][i * 16 + llo] = s;
  }
  if (w >= 2) {
#pragma unroll
    for (int i = 0; i < 4; ++i)
#pragma unroll
      for (int j = 0; j < 4; ++j)
        *(f32x4*)(red + (((w - 2) * 16 + i * 4 + j) << 8) + ll * 4) = acc[i][j];
  }
  __syncthreads();
  if (w < 2) {
#pragma unroll
    for (int i = 0; i < 4; ++i)
#pragma unroll
      for (int j = 0; j < 4; ++j)
        acc[i][j] += *(const f32x4*)(red + ((w * 16 + i * 4 + j) << 8) + ll * 4);
  }
  float ksv = 0.f;
  if (w == 1) ksv = ksred[0][ll] + ksred[1][ll] + ksred[2][ll] + ksred[3][ll];
  __syncthreads();
  if (w == 1) {
#pragma unroll
    for (int i = 0; i < 4; ++i)
#pragma unroll
      for (int j = 0; j < 4; ++j)
        *(f32x4*)(red + ((i * 4 + j) << 8) + ll * 4) = acc[i][j];
    part_ks[((size_t)lc * 64 + bh) * 64 + ll] = ksv;
  }
  __syncthreads();
  if (w == 0) {
    float* op = part + ((size_t)lc * 64 + bh) * 4096;
#pragma unroll
    for (int i = 0; i < 4; ++i)
#pragma unroll
      for (int j = 0; j < 4; ++j) {
        acc[i][j] += *(const f32x4*)(red + ((i * 4 + j) << 8) + ll * 4);
#pragma unroll
        for (int r = 0; r < 4; ++r) {
          int d = i * 16 + lhi * 4 + r, v = j * 16 + llo;
          op[d * 64 + v] = acc[i][j][r];
        }
      }
  }
}

// ---- merged reduction: kv (262144 elems) + ksum (4096 elems) in one launch ----
__global__ void red_k(const float* __restrict__ part, const float* __restrict__ pks,
                      float* __restrict__ kv, float* __restrict__ ksum) {
  const int bid = blockIdx.x;
  const int t = threadIdx.x;
  if (bid < 1024) {
    const int i = bid * 256 + t;
    float s = 0.f;
#pragma unroll
    for (int lc = 0; lc < 8; ++lc) s += part[(size_t)lc * 262144 + i];
    kv[i] = s;
  } else {
    const int i = (bid - 1024) * 256 + t;
    float s = 0.f;
#pragma unroll
    for (int lc = 0; lc < 8; ++lc) s += pks[(size_t)lc * 4096 + i];
    ksum[i] = s;
  }
}

// ---------------- apply: attn[b][l][h*64+v] = (sum_d Q[l,d]KV[d,v]) * Z[l] ----------------
__global__ __launch_bounds__(256) void apply_k(const __bf16* __restrict__ qt,
                                               const float* __restrict__ kv,
                                               const float* __restrict__ ksum,
                                               __bf16* __restrict__ attn) {
  __shared__ __attribute__((aligned(16))) __bf16 kvT[64 * 68];
  __shared__ float zb[256];
  const int lc = blockIdx.x, bh = blockIdx.y;
  const int b = bh >> 3, h = bh & 7;
  const int tid = threadIdx.x;
  const float* kvp = kv + (size_t)bh * 4096;
  for (int i = tid; i < 4096; i += 256) {
    int d = i >> 6, v = i & 63;
    kvT[v * 68 + d] = (__bf16)kvp[i];
  }
  const int l = lc * 256 + tid;
  const __bf16* qp = qt + ((size_t)b * LLEN + l) * CCH + h * 64;
  const float* ksp = ksum + bh * 64;
  float s = 0.f;
#pragma unroll
  for (int d8 = 0; d8 < 64; d8 += 8) {
    bf16x8 qv = *(const bf16x8*)(qp + d8);
#pragma unroll
    for (int i = 0; i < 8; ++i) s += (float)qv[i] * ksp[d8 + i];
  }
  zb[tid] = 1.0f / (s + 1e-6f);
  __syncthreads();

  const int ll = tid & 63, w = tid >> 6, lhi = ll >> 4, llo = ll & 15;
  f32x4 acc[4][4];
#pragma unroll
  for (int i = 0; i < 4; ++i)
#pragma unroll
    for (int j = 0; j < 4; ++j) acc[i][j] = (f32x4){0.f, 0.f, 0.f, 0.f};
  const __bf16* qbase = qt + ((size_t)b * LLEN + lc * 256 + w * 64) * CCH + h * 64;
#pragma unroll
  for (int kt = 0; kt < 2; ++kt) {
    const int k8 = kt * 32 + lhi * 8;
    bf16x8 af[4], bfr[4];
#pragma unroll
    for (int i = 0; i < 4; ++i)
      af[i] = *(const bf16x8*)(qbase + (size_t)(i * 16 + llo) * CCH + k8);
#pragma unroll
    for (int j = 0; j < 4; ++j) {
      const __bf16* pb = kvT + (j * 16 + llo) * 68 + k8;
      ((bf16x4*)&bfr[j])[0] = *(const bf16x4*)pb;
      ((bf16x4*)&bfr[j])[1] = *(const bf16x4*)(pb + 4);
    }
#pragma unroll
    for (int i = 0; i < 4; ++i)
#pragma unroll
      for (int j = 0; j < 4; ++j) acc[i][j] = mfma16(af[i], bfr[j], acc[i][j]);
  }
  __bf16* ap = attn + ((size_t)b * LLEN + lc * 256) * CCH + h * 64;
#pragma unroll
  for (int i = 0; i < 4; ++i)
#pragma unroll
    for (int j = 0; j < 4; ++j)
#pragma unroll
      for (int r = 0; r < 4; ++r) {
        int ml = w * 64 + i * 16 + lhi * 4 + r;
        int v = j * 16 + llo;
        ap[(size_t)ml * CCH + v] = (__bf16)(acc[i][j][r] * zb[ml]);
      }
}

extern "C" void kernel_launch(void* const* d_in, const int* in_sizes, int n_in,
                              void* d_out, int out_size, void* d_ws, size_t ws_size,
                              hipStream_t stream) {
  const float* x  = (const float*)d_in[0];
  const float* wq = (const float*)d_in[1];
  const float* bq = (const float*)d_in[2];
  const float* wk = (const float*)d_in[3];
  const float* bk = (const float*)d_in[4];
  const float* wv = (const float*)d_in[5];
  const float* bv = (const float*)d_in[6];
  const float* wo = (const float*)d_in[7];
  const float* bo = (const float*)d_in[8];
  float* out = (float*)d_out;

  char* p = (char*)d_ws;
  __bf16* xt    = (__bf16*)p; p += (size_t)BATCH * LLEN * CCH * 2;  // 32MB (reused as attn)
  __bf16* qt    = (__bf16*)p; p += (size_t)BATCH * LLEN * CCH * 2;  // 32MB
  __bf16* kcm   = (__bf16*)p; p += (size_t)BATCH * CCH * LLEN * 2;  // 32MB
  __bf16* vcm   = (__bf16*)p; p += (size_t)BATCH * CCH * LLEN * 2;  // 32MB
  __bf16* wqkvb = (__bf16*)p; p += (size_t)M1 * CCH * 2;
  __bf16* wob   = (__bf16*)p; p += (size_t)CCH * CCH * 2;
  float*  biasq = (float*)p;  p += (size_t)M1 * 4;
  float*  ksum  = (float*)p;  p += (size_t)BATCH * CCH * 4;
  float*  part  = (float*)p;  p += (size_t)8 * 64 * HD * HD * 4;    // 8MB
  float*  kvb   = (float*)p;  p += (size_t)64 * HD * HD * 4;        // 1MB
  float*  pks   = (float*)p;  p += (size_t)8 * 64 * 64 * 4;         // 128KB
  __bf16* attn  = xt;

  pack_w<<<1024, 256, 0, stream>>>(wq, wk, wv, wo, bq, bk, bv, wqkvb, wob, biasq);
  transpose_x<<<dim3(64, 8, BATCH), 256, 0, stream>>>(x, xt);
  gemm128t<0><<<dim3(32, 12, BATCH), 256, 0, stream>>>(wqkvb, xt, biasq, qt, kcm, vcm, nullptr);
  kv_part_k<<<dim3(8, 64), 256, 0, stream>>>(kcm, vcm, part, pks);
  red_k<<<1040, 256, 0, stream>>>(part, pks, kvb, ksum);
  apply_k<<<dim3(16, 64), 256, 0, stream>>>(qt, kvb, ksum, attn);
  gemm128t<1><<<dim3(32, 4, BATCH), 256, 0, stream>>>(wob, attn, bo, nullptr, nullptr,
                                                      nullptr, out);
}